// Round 1
// baseline (181.850 us; speedup 1.0000x reference)
//
#include <hip/hip_runtime.h>

#define NN 8192
#define STEPS 512

// Kernel 1: h = W @ x0. One wave (64 lanes) per row, float4 loads.
// All values are small integers (|h| <= 8191) -> exact in f32 at any order.
__global__ __launch_bounds__(256) void hopfield_matvec(
    const float* __restrict__ W, const float* __restrict__ x,
    float* __restrict__ h) {
  const int wave = threadIdx.x >> 6;
  const int lane = threadIdx.x & 63;
  const int row  = (blockIdx.x << 2) + wave;
  const float4* __restrict__ Wr = (const float4*)(W + (size_t)row * NN);
  const float4* __restrict__ xv = (const float4*)x;
  float acc = 0.f;
#pragma unroll 8
  for (int it = 0; it < (NN / 4 / 64); ++it) {
    const float4 w  = Wr[it * 64 + lane];
    const float4 xx = xv[it * 64 + lane];
    acc += w.x * xx.x + w.y * xx.y + w.z * xx.z + w.w * xx.w;
  }
#pragma unroll
  for (int off = 32; off; off >>= 1) acc += __shfl_down(acc, off);
  if (lane == 0) h[row] = acc;
}

// Kernel 2: sequential Hopfield updates with incremental h and energy.
// Single block of 1024 threads; h, x, idx, energies live in LDS.
__global__ __launch_bounds__(1024) void hopfield_seq(
    const float* __restrict__ W, const float* __restrict__ x0,
    const int* __restrict__ idx, const float* __restrict__ h_in,
    float* __restrict__ out) {
  __shared__ __align__(16) float hs[NN];
  __shared__ __align__(16) float xs[NN];
  __shared__ int   idx_s[STEPS];
  __shared__ float es[STEPS];
  __shared__ int   s_S;

  const int tid = threadIdx.x;

  // Stage inputs into LDS.
#pragma unroll
  for (int k = 0; k < 8; ++k) {
    const int j = tid + k * 1024;
    hs[j] = h_in[j];
    xs[j] = x0[j];
  }
  if (tid < STEPS) idx_s[tid] = idx[tid];
  if (tid == 0) s_S = 0;
  __syncthreads();

  // S = x^T (W x) as exact integer.
  int part = 0;
#pragma unroll
  for (int k = 0; k < 8; ++k) {
    const int j = tid + k * 1024;
    part += (int)xs[j] * (int)hs[j];
  }
#pragma unroll
  for (int off = 32; off; off >>= 1) part += __shfl_down(part, off);
  if ((tid & 63) == 0) atomicAdd(&s_S, part);
  __syncthreads();

  long long S = (long long)s_S;  // uniform across all threads

  for (int t = 0; t < STEPS; ++t) {
    const int   i  = idx_s[t];
    const float hi = hs[i];   // LDS broadcast (uniform address)
    const float xi = xs[i];
    const int act = (hi > 0.f) ? 1 : ((hi < 0.f) ? -1 : 0);
    const int xsg = (xi > 0.f) ? 1 : ((xi < 0.f) ? -1 : 0);
    const int xiv = (int)xi;
    const int newv = (xsg != act) ? act : xiv;
    const int dlt = newv - xiv;  // in {-2, 0, 2}; uniform across all threads

    if (dlt != 0) {  // wave-uniform branch (same data for all threads)
      __syncthreads();  // everyone has read hs[i], xs[i] for this step
      const float4* __restrict__ Wr = (const float4*)(W + (size_t)i * NN);
      const float fd = (float)dlt;
#pragma unroll
      for (int k = 0; k < 2; ++k) {
        const int j4 = tid + k * 1024;  // 2048 float4 = 8192 floats
        const float4 w = Wr[j4];
        float4* hp = ((float4*)hs) + j4;
        float4 hv = *hp;
        hv.x += fd * w.x; hv.y += fd * w.y;
        hv.z += fd * w.z; hv.w += fd * w.w;
        *hp = hv;
      }
      if (tid == 0) xs[i] = (float)newv;
      const int wii = (int)W[(size_t)i * NN + i];
      S += (long long)(2 * dlt) * (long long)(int)hi
         + (long long)(dlt * dlt) * (long long)wii;
      __syncthreads();  // h update visible before next step's reads
    }
    if (tid == 0) es[t] = -0.5f * (float)S;
  }
  __syncthreads();

  // Write outputs: x_final (NN floats) then energies (STEPS floats).
#pragma unroll
  for (int k = 0; k < 8; ++k) {
    const int j = tid + k * 1024;
    out[j] = xs[j];
  }
  if (tid < STEPS) out[NN + tid] = es[tid];
}

extern "C" void kernel_launch(void* const* d_in, const int* in_sizes, int n_in,
                              void* d_out, int out_size, void* d_ws, size_t ws_size,
                              hipStream_t stream) {
  const float* x   = (const float*)d_in[0];  // x_noisy (8192,1) f32
  const float* W   = (const float*)d_in[1];  // weights (8192,8192) f32
  const int*   idx = (const int*)d_in[2];    // idx (512,) i32
  float* out = (float*)d_out;                // [x_final (8192) | energies (512)]
  float* h   = (float*)d_ws;                 // 32 KB scratch for h = W @ x0

  hopfield_matvec<<<NN / 4, 256, 0, stream>>>(W, x, h);
  hopfield_seq<<<1, 1024, 0, stream>>>(W, x, idx, h, out);
}

// Round 2
// 101.559 us; speedup vs baseline: 1.7906x; 1.7906x over previous
//
#include <hip/hip_runtime.h>

#define NN 8192
#define STEPS 512

// Kernel 1: h = W @ x0. One wave (64 lanes) per row, float4 loads.
// All values are small integers (|h| <= 8191) -> exact in f32 at any order.
__global__ __launch_bounds__(256) void hopfield_matvec(
    const float* __restrict__ W, const float* __restrict__ x,
    float* __restrict__ h) {
  const int wave = threadIdx.x >> 6;
  const int lane = threadIdx.x & 63;
  const int row  = (blockIdx.x << 2) + wave;
  const float4* __restrict__ Wr = (const float4*)(W + (size_t)row * NN);
  const float4* __restrict__ xv = (const float4*)x;
  float acc = 0.f;
#pragma unroll 8
  for (int it = 0; it < (NN / 4 / 64); ++it) {
    const float4 w  = Wr[it * 64 + lane];
    const float4 xx = xv[it * 64 + lane];
    acc += w.x * xx.x + w.y * xx.y + w.z * xx.z + w.w * xx.w;
  }
#pragma unroll
  for (int off = 32; off; off >>= 1) acc += __shfl_down(acc, off);
  if (lane == 0) h[row] = acc;
}

// Kernel 2: batched-flip sequential dynamics. Key identity: between flips,
// (h, x) are constant, so every pending step's flip decision can be
// evaluated IN PARALLEL (thread t owns step t). Find first flipping step
// via LDS atomicMin, emit the uniform energy for all skipped steps, apply
// the one flip (h += d*W[i,:], exact integer S += 2*d*h_i; W_ii==0), repeat.
// ~#flips (~51) iterations instead of 512 sequential steps.
__global__ __launch_bounds__(1024) void hopfield_seq(
    const float* __restrict__ W, const float* __restrict__ x0,
    const int* __restrict__ idx, const float* __restrict__ h_in,
    float* __restrict__ out) {
  __shared__ __align__(16) float hs[NN];
  __shared__ __align__(16) float xs[NN];
  __shared__ int   idx_s[STEPS];
  __shared__ float es[STEPS];
  __shared__ int   s_S;
  __shared__ int   s_first;

  const int tid = threadIdx.x;

  // Stage inputs into LDS.
#pragma unroll
  for (int k = 0; k < 8; ++k) {
    const int j = tid + k * 1024;
    hs[j] = h_in[j];
    xs[j] = x0[j];
  }
  if (tid < STEPS) idx_s[tid] = idx[tid];
  if (tid == 0) s_S = 0;
  __syncthreads();

  // S = x^T (W x) as exact integer.
  int part = 0;
#pragma unroll
  for (int k = 0; k < 8; ++k) {
    const int j = tid + k * 1024;
    part += (int)xs[j] * (int)hs[j];
  }
#pragma unroll
  for (int off = 32; off; off >>= 1) part += __shfl_down(part, off);
  if ((tid & 63) == 0) atomicAdd(&s_S, part);
  __syncthreads();

  long long S = (long long)s_S;  // uniform across all threads

  const int myI = (tid < STEPS) ? idx_s[tid] : 0;  // step owned by this thread

  int pos = 0;
  for (;;) {
    __syncthreads();                    // A: h/x updates visible; prior s_first reads done
    if (tid == 0) s_first = STEPS;
    __syncthreads();                    // B: reset visible
    if (tid >= pos && tid < STEPS) {
      const float hi = hs[myI];
      const float xi = xs[myI];
      if ((xi > 0.f) != (hi > 0.f)) atomicMin(&s_first, tid);
    }
    __syncthreads();                    // C: s_first final
    const int t1 = s_first;             // first flipping step (uniform), or STEPS
    const float E = -0.5f * (float)S;
    if (tid >= pos && tid < t1) es[tid] = E;  // skipped steps: energy unchanged
    if (t1 >= STEPS) break;

    // Process the flip at step t1 (all values uniform across threads).
    const int   i  = idx_s[t1];
    const float hi = hs[i];
    const float xi = xs[i];
    const int act  = (hi > 0.f) ? 1 : -1;
    const int d    = act - (int)xi;     // ±2
    __syncthreads();                    // D: uniform reads done before h update

    const float fd = (float)d;
    const float4* __restrict__ Wr = (const float4*)(W + (size_t)i * NN);
#pragma unroll
    for (int k = 0; k < 2; ++k) {
      const int j4 = tid + k * 1024;    // 2048 float4 = 8192 floats
      const float4 w = Wr[j4];
      float4* hp = ((float4*)hs) + j4;
      float4 hv = *hp;
      hv.x += fd * w.x; hv.y += fd * w.y;
      hv.z += fd * w.z; hv.w += fd * w.w;
      *hp = hv;
    }
    S += (long long)(2 * d) * (long long)(int)hi;  // W_ii == 0 by construction
    if (tid == 0) {
      xs[i] = (float)act;
      es[t1] = -0.5f * (float)S;
    }
    pos = t1 + 1;
  }
  __syncthreads();

  // Write outputs: x_final (NN floats) then energies (STEPS floats).
#pragma unroll
  for (int k = 0; k < 8; ++k) {
    const int j = tid + k * 1024;
    out[j] = xs[j];
  }
  if (tid < STEPS) out[NN + tid] = es[tid];
}

extern "C" void kernel_launch(void* const* d_in, const int* in_sizes, int n_in,
                              void* d_out, int out_size, void* d_ws, size_t ws_size,
                              hipStream_t stream) {
  const float* x   = (const float*)d_in[0];  // x_noisy (8192,1) f32
  const float* W   = (const float*)d_in[1];  // weights (8192,8192) f32
  const int*   idx = (const int*)d_in[2];    // idx (512,) i32
  float* out = (float*)d_out;                // [x_final (8192) | energies (512)]
  float* h   = (float*)d_ws;                 // 32 KB scratch for h = W @ x0

  hopfield_matvec<<<NN / 4, 256, 0, stream>>>(W, x, h);
  hopfield_seq<<<1, 1024, 0, stream>>>(W, x, idx, h, out);
}